// Round 10
// baseline (138.387 us; speedup 1.0000x reference)
//
#include <hip/hip_runtime.h>

#define M_NODES 16384
#define NNBR 32
#define RREL 237
#define ATTN_SCALE 0.25f   // (128/8)^-0.5
#define LN_EPS 1e-5f

typedef float float4v __attribute__((ext_vector_type(4)));
typedef unsigned int uint4v __attribute__((ext_vector_type(4)));
typedef short short8 __attribute__((ext_vector_type(8)));
typedef float floatx4 __attribute__((ext_vector_type(4)));

__device__ __forceinline__ float bfu2f(unsigned short u) {
    return __builtin_bit_cast(float, ((unsigned int)u) << 16);
}
__device__ __forceinline__ unsigned short f2bfu(float f) {
    unsigned int x = __builtin_bit_cast(unsigned int, f);
    unsigned int lsb = (x >> 16) & 1u;
    x += 0x7fffu + lsb;                 // round-to-nearest-even
    return (unsigned short)(x >> 16);
}
__device__ __forceinline__ unsigned int pack2(float a, float b) {
    return (unsigned int)f2bfu(a) | ((unsigned int)f2bfu(b) << 16);
}
__device__ __forceinline__ float unpk_lo(unsigned int u) {
    return __builtin_bit_cast(float, u << 16);
}
__device__ __forceinline__ float unpk_hi(unsigned int u) {
    return __builtin_bit_cast(float, u & 0xffff0000u);
}

// ===========================================================================
// FAST PATH — 4 dispatches. Cost model: wall = ~40 fixed + ~45 ws-fill
// + sum(kernels). Never use device barriers (r11).
// r21 (confirmed, 136.8->130.9): K2 was TCP address-divergence-bound; K/R
// rows now loaded row-contiguously + LDS transpose to fragment layout.
// r22: register-pressure fix. r21 issued K+R loads together (peak ~95 VGPR
// vs 85 cap at lb(256,6) -> spill risk). R table is L1/L2-hot (60KB), so R
// loads move to after K-h1 staging (rreg reuses kreg's registers); peak
// drops to ~65 VGPR -> clean lb(256,7) (r17's proven occupancy point).
// ===========================================================================

// K0: weight transpose+convert (blocks 0..31) + entity fp32->bf16 (32..159)
//     + neighbor (mask,idx,rel) -> packed PIX (160..223).
__global__ __launch_bounds__(256) void prep_w(
    const float* __restrict__ Wq, const float* __restrict__ Wk,
    const float* __restrict__ Wv, const float* __restrict__ Wo,
    const float* __restrict__ entity,
    const int* __restrict__ nidx, const int* __restrict__ nrel,
    const int* __restrict__ nmask,
    unsigned short* __restrict__ WqT, unsigned short* __restrict__ WkT,
    unsigned short* __restrict__ WvT, unsigned short* __restrict__ WoT,
    unsigned short* __restrict__ Eb, unsigned int* __restrict__ PIX) {
    int t = threadIdx.x;
    if (blockIdx.x < 32) {
        int mat  = blockIdx.x >> 3;
        int slab = blockIdx.x & 7;
        const float* W = (mat == 0) ? Wq : (mat == 1) ? Wk : (mat == 2) ? Wv : Wo;
        unsigned short* WT = (mat == 0) ? WqT : (mat == 1) ? WkT : (mat == 2) ? WvT : WoT;
        #pragma unroll
        for (int i = 0; i < 8; ++i) {
            int idx = t + 256 * i;
            int r = slab * 16 + (idx >> 7);
            int c = idx & 127;
            WT[c * 128 + r] = f2bfu(W[r * 128 + c]);
        }
    } else if (blockIdx.x < 160) {
        // 128 blocks x 256 thr x 8 iters x 8 elems = 16384*128 elements
        int b = blockIdx.x - 32;
        const float* src = entity + (size_t)b * 16384;
        unsigned short* dst = Eb + (size_t)b * 16384;
        #pragma unroll
        for (int i = 0; i < 8; ++i) {
            int o = (i * 256 + t) * 8;
            float4v f0 = *(const float4v*)&src[o];
            float4v f1 = *(const float4v*)&src[o + 4];
            short8 s;
            #pragma unroll
            for (int j = 0; j < 4; ++j) {
                s[j]     = (short)f2bfu(f0[j]);
                s[4 + j] = (short)f2bfu(f1[j]);
            }
            *(short8*)&dst[o] = s;
        }
    } else {
        // 64 blocks x 256 thr x 32 entries = 524288 packed neighbor records
        int base = (blockIdx.x - 160) * 8192;
        #pragma unroll 8
        for (int i = 0; i < 32; ++i) {
            int e = base + i * 256 + t;
            int mk = nmask[e];
            int ix = nidx[e];
            int ir = nrel[e];
            if (!mk) { ix = 0; ir = 0; }
            ix = ix < 0 ? 0 : (ix > M_NODES - 1 ? M_NODES - 1 : ix);
            ir = ir < 0 ? 0 : (ir > RREL - 1 ? RREL - 1 : ir);
            PIX[e] = (unsigned)ix | ((unsigned)ir << 14) | (mk ? 0x80000000u : 0u);
        }
    }
}

// K1: four projections. grid (256, 4), 64 rows/block (proven r1 form):
//   y=0: EQb; y=1: Kb; y=2: Vb; y=3: RKb (237 rows).
__global__ __launch_bounds__(256) void gemm4_mfma(
    const float* __restrict__ rel_table, const unsigned short* __restrict__ Eb,
    const unsigned short* __restrict__ WqT, const unsigned short* __restrict__ WkT,
    const unsigned short* __restrict__ WvT,
    const float* __restrict__ bq, const float* __restrict__ bk,
    const float* __restrict__ bv,
    unsigned short* __restrict__ EQb, unsigned short* __restrict__ Kb,
    unsigned short* __restrict__ Vb, unsigned short* __restrict__ RKb) {
    __shared__ __align__(16) unsigned short lw[128 * 136];

    int y = blockIdx.y;
    const unsigned short* WT; const float* bias; int arows;
    unsigned short* outb;
    if (y == 0)      { WT = WqT; bias = bq;      arows = M_NODES; outb = EQb; }
    else if (y == 1) { WT = WkT; bias = nullptr; arows = M_NODES; outb = Kb;  }
    else if (y == 2) { WT = WvT; bias = bv;      arows = M_NODES; outb = Vb;  }
    else             { WT = WkT; bias = bk;      arows = RREL;    outb = RKb; }

    int rbase = blockIdx.x * 64;
    if (rbase >= arows) return;
    int t = threadIdx.x;
    int wave = t >> 6, lane = t & 63;
    int lm = lane & 15, quad = lane >> 4;
    int m0 = rbase + wave * 16;
    int r0 = m0 + lm; if (r0 >= arows) r0 = arows - 1;

    // A-fragments hoisted before staging: loads fly under the LDS fill.
    short8 af[4];
    if (y == 3) {
        #pragma unroll
        for (int ks = 0; ks < 4; ++ks) {
            int koff = ks * 32 + quad * 8;
            float4v f0 = *(const float4v*)&rel_table[r0 * 128 + koff];
            float4v f1 = *(const float4v*)&rel_table[r0 * 128 + koff + 4];
            #pragma unroll
            for (int j = 0; j < 4; ++j) {
                af[ks][j]     = (short)f2bfu(f0[j]);
                af[ks][4 + j] = (short)f2bfu(f1[j]);
            }
        }
    } else {
        #pragma unroll
        for (int ks = 0; ks < 4; ++ks)
            af[ks] = *(const short8*)&Eb[r0 * 128 + ks * 32 + quad * 8];
    }

    #pragma unroll
    for (int i = 0; i < 8; ++i) {
        int ci = t + 256 * i;
        int r  = ci >> 4;
        int c8 = ci & 15;
        *(short8*)&lw[r * 136 + c8 * 8] = *(const short8*)&WT[r * 128 + c8 * 8];
    }
    __syncthreads();

    floatx4 acc[8];
    #pragma unroll
    for (int c = 0; c < 8; ++c) acc[c] = (floatx4){0.f, 0.f, 0.f, 0.f};

    #pragma unroll
    for (int ks = 0; ks < 4; ++ks) {
        int koff = ks * 32 + quad * 8;
        #pragma unroll
        for (int c = 0; c < 8; ++c) {
            short8 b = *(const short8*)&lw[(c * 16 + lm) * 136 + koff];
            acc[c] = __builtin_amdgcn_mfma_f32_16x16x32_bf16(af[ks], b, acc[c], 0, 0, 0);
        }
    }

    #pragma unroll
    for (int c = 0; c < 8; ++c) {
        int col = c * 16 + lm;
        float bb = bias ? bias[col] : 0.0f;
        int rb = m0 + quad * 4;
        #pragma unroll
        for (int j = 0; j < 4; ++j) {
            int r = rb + j;
            if (r < arows) outb[r * 128 + col] = f2bfu(acc[c][j] + bb);
        }
    }
}

// K2: wave-per-node attention. grid 4096 x 256 (4 nodes/block).
// r21: K/R rows loaded ROW-CONTIGUOUSLY then transposed to MFMA fragment
// layout via a 16-row wave-private LDS half-buffer (272B stride), reused
// for K-h0/K-h1/R-h0/R-h1. r22: R loads issued AFTER K-h1 staging (kreg
// dead -> rreg reuses its registers; R is L1/L2-hot so short latency hides
// under K-h1 consume). V loads after R-h1 staging. Peak ~65 VGPR -> (256,7).
// fp32 accum order unchanged vs r9 (bit-identical).
__global__ __launch_bounds__(256, 7) void attn_gather(
    const unsigned int* __restrict__ PIX,
    const unsigned short* __restrict__ EQb, const unsigned short* __restrict__ Kb,
    const unsigned short* __restrict__ Vb, const unsigned short* __restrict__ RKb,
    unsigned short* __restrict__ OATb) {
    __shared__ float Pl[4][8][33];
    __shared__ __align__(16) unsigned short Kst[4][16 * 136];   // 4.25KB/wave

    int w = threadIdx.x >> 6, l = threadIdx.x & 63;
    int m = blockIdx.x * 4 + w;
    int lm = l & 15, quad = l >> 4;
    int n0 = l & 31;
    int cs = l & 15;     // chunk slot (16B units within a 256B row)
    int rs = l >> 4;     // row slot (4 rows per load instruction)

    // ---- single packed neighbor record: ix(14) | ir(8)<<14 | mk<<31 ----
    unsigned pix = PIX[m * NNBR + n0];

    // q depends only on m — wave-uniform row, 1 segment per load.
    short8 q8v[4];
    #pragma unroll
    for (int ks = 0; ks < 4; ++ks)
        q8v[ks] = *(const short8*)&EQb[m * 128 + ks * 32 + quad * 8];

    int ix = (int)(pix & 0x3FFFu);
    int ir = (int)((pix >> 14) & 0xFFu);
    unsigned long long bal = __ballot((pix >> 31) != 0);
    unsigned maskbits = (unsigned)(bal & 0xffffffffu);   // bit n = mask of nbr n

    // ---- row-contiguous K loads (L2-miss, latency-critical: all up-front) --
    short8 kreg[8];
    #pragma unroll
    for (int i = 0; i < 8; ++i) {
        int rK = __shfl(ix, i * 4 + rs, 64);
        kreg[i] = *(const short8*)&Kb[rK * 128 + cs * 8];
    }

    floatx4 acc0 = (floatx4){0.f, 0.f, 0.f, 0.f};
    floatx4 acc1 = (floatx4){0.f, 0.f, 0.f, 0.f};
    const short8 zero8 = (short8){0, 0, 0, 0, 0, 0, 0, 0};
    unsigned short* kw = &Kst[w][0];

    // ---- K half 0 (rows 0..15) : stage -> consume ----
    #pragma unroll
    for (int i = 0; i < 4; ++i)
        *(short8*)&kw[(i * 4 + rs) * 136 + cs * 8] = kreg[i];
    #pragma unroll
    for (int ks = 0; ks < 4; ++ks) {
        int h = ks * 2 + (quad >> 1);
        short8 bq = (lm == h) ? q8v[ks] : zero8;
        short8 kf = *(const short8*)&kw[lm * 136 + (ks * 4 + quad) * 8];
        acc0 = __builtin_amdgcn_mfma_f32_16x16x32_bf16(kf, bq, acc0, 0, 0, 0);
    }
    // ---- K half 1 staging (rows 16..31) — kreg dies here ----
    #pragma unroll
    for (int i = 0; i < 4; ++i)
        *(short8*)&kw[(i * 4 + rs) * 136 + cs * 8] = kreg[4 + i];

    // ---- R loads issued now (registers reused from kreg; L1/L2-hot table,
    //      latency hides under K-h1 consume + TLP) ----
    short8 rreg[8];
    #pragma unroll
    for (int i = 0; i < 8; ++i) {
        int rR = __shfl(ir, i * 4 + rs, 64);
        rreg[i] = *(const short8*)&RKb[rR * 128 + cs * 8];
    }

    // ---- K half 1 consume ----
    #pragma unroll
    for (int ks = 0; ks < 4; ++ks) {
        int h = ks * 2 + (quad >> 1);
        short8 bq = (lm == h) ? q8v[ks] : zero8;
        short8 kf = *(const short8*)&kw[lm * 136 + (ks * 4 + quad) * 8];
        acc1 = __builtin_amdgcn_mfma_f32_16x16x32_bf16(kf, bq, acc1, 0, 0, 0);
    }
    // ---- R half 0 ----
    #pragma unroll
    for (int i = 0; i < 4; ++i)
        *(short8*)&kw[(i * 4 + rs) * 136 + cs * 8] = rreg[i];
    #pragma unroll
    for (int ks = 0; ks < 4; ++ks) {
        int h = ks * 2 + (quad >> 1);
        short8 bq = (lm == h) ? q8v[ks] : zero8;
        short8 rf = *(const short8*)&kw[lm * 136 + (ks * 4 + quad) * 8];
        acc0 = __builtin_amdgcn_mfma_f32_16x16x32_bf16(rf, bq, acc0, 0, 0, 0);
    }
    // ---- R half 1 staging — rreg dies here ----
    #pragma unroll
    for (int i = 0; i < 4; ++i)
        *(short8*)&kw[(i * 4 + rs) * 136 + cs * 8] = rreg[4 + i];

    // ---- V gather issued now (row-contiguous; latency hides under R-h1
    //      consume + softmax VALU) ----
    uint4v vreg[8];
    #pragma unroll
    for (int i = 0; i < 8; ++i) {
        int ixx = __shfl(ix, quad + i * 4, 64);
        vreg[i] = *(const uint4v*)&Vb[ixx * 128 + lm * 8];
    }

    // ---- R half 1 consume ----
    #pragma unroll
    for (int ks = 0; ks < 4; ++ks) {
        int h = ks * 2 + (quad >> 1);
        short8 bq = (lm == h) ? q8v[ks] : zero8;
        short8 rf = *(const short8*)&kw[lm * 136 + (ks * 4 + quad) * 8];
        acc1 = __builtin_amdgcn_mfma_f32_16x16x32_bf16(rf, bq, acc1, 0, 0, 0);
    }

    // ---- masked softmax in C-layout (head = lm, n = g*16 + quad*4 + j) ----
    float lf[2][4];
    #pragma unroll
    for (int j = 0; j < 4; ++j) {
        int na = quad * 4 + j, nb = 16 + quad * 4 + j;
        float va = acc0[j] * ATTN_SCALE;
        float vb = acc1[j] * ATTN_SCALE;
        lf[0][j] = ((maskbits >> na) & 1) ? va : -1e30f;
        lf[1][j] = ((maskbits >> nb) & 1) ? vb : -1e30f;
    }
    float mx = -1e30f;
    #pragma unroll
    for (int g = 0; g < 2; ++g)
        #pragma unroll
        for (int j = 0; j < 4; ++j) mx = fmaxf(mx, lf[g][j]);
    mx = fmaxf(mx, __shfl_xor(mx, 16, 64));
    mx = fmaxf(mx, __shfl_xor(mx, 32, 64));
    float p[2][4];
    float s = 0.f;
    #pragma unroll
    for (int g = 0; g < 2; ++g)
        #pragma unroll
        for (int j = 0; j < 4; ++j) { p[g][j] = __expf(lf[g][j] - mx); s += p[g][j]; }
    s += __shfl_xor(s, 16, 64);
    s += __shfl_xor(s, 32, 64);
    float inv = 1.0f / s;
    if (lm < 8) {
        #pragma unroll
        for (int g = 0; g < 2; ++g)
            #pragma unroll
            for (int j = 0; j < 4; ++j)
                Pl[w][lm][g * 16 + quad * 4 + j] = p[g][j] * inv;
    }

    // ---- PV from vreg (same-wave LDS, no barrier); hi/lo unpack ----
    float o[8] = {0.f, 0.f, 0.f, 0.f, 0.f, 0.f, 0.f, 0.f};
    #pragma unroll
    for (int i = 0; i < 8; ++i) {
        float pp = Pl[w][lm >> 1][quad + i * 4];
        uint4v v = vreg[i];
        #pragma unroll
        for (int k = 0; k < 4; ++k) {
            o[2 * k]     += pp * unpk_lo(v[k]);
            o[2 * k + 1] += pp * unpk_hi(v[k]);
        }
    }
    #pragma unroll
    for (int j = 0; j < 8; ++j) {
        o[j] += __shfl_xor(o[j], 16, 64);
        o[j] += __shfl_xor(o[j], 32, 64);
    }
    if (quad == 0) {
        uint4v u;
        u[0] = pack2(o[0], o[1]); u[1] = pack2(o[2], o[3]);
        u[2] = pack2(o[4], o[5]); u[3] = pack2(o[6], o[7]);
        *(uint4v*)&OATb[m * 128 + lm * 8] = u;
    }
}

// K3: Y = OATb@Wo + bo + entity -> LayerNorm. grid 256, 256 thr
// (4 waves x 16 rows; B staged in LDS — proven r1 form).
__global__ __launch_bounds__(256) void gemm_wo_ln(
    const unsigned short* __restrict__ OATb, const unsigned short* __restrict__ WoT,
    const float* __restrict__ bo, const float* __restrict__ entity,
    const float* __restrict__ gamma_, const float* __restrict__ beta_,
    float* __restrict__ OUT) {
    __shared__ __align__(16) unsigned short lw[128 * 136];

    int t = threadIdx.x;
    int wave = t >> 6, lane = t & 63;
    int lm = lane & 15, quad = lane >> 4;
    int m0 = blockIdx.x * 64 + wave * 16;
    int r0 = m0 + lm;

    // A-fragments hoisted before staging.
    short8 af[4];
    #pragma unroll
    for (int ks = 0; ks < 4; ++ks)
        af[ks] = *(const short8*)&OATb[r0 * 128 + ks * 32 + quad * 8];

    #pragma unroll
    for (int i = 0; i < 8; ++i) {
        int ci = t + 256 * i;
        int r  = ci >> 4;
        int c8 = ci & 15;
        *(short8*)&lw[r * 136 + c8 * 8] = *(const short8*)&WoT[r * 128 + c8 * 8];
    }
    __syncthreads();

    floatx4 acc[8];
    #pragma unroll
    for (int c = 0; c < 8; ++c) acc[c] = (floatx4){0.f, 0.f, 0.f, 0.f};

    #pragma unroll
    for (int ks = 0; ks < 4; ++ks) {
        int koff = ks * 32 + quad * 8;
        #pragma unroll
        for (int c = 0; c < 8; ++c) {
            short8 b = *(const short8*)&lw[(c * 16 + lm) * 136 + koff];
            acc[c] = __builtin_amdgcn_mfma_f32_16x16x32_bf16(af[ks], b, acc[c], 0, 0, 0);
        }
    }

    float bb[8], gg[8], be[8];
    #pragma unroll
    for (int c = 0; c < 8; ++c) {
        int col = c * 16 + lm;
        bb[c] = bo[col]; gg[c] = gamma_[col]; be[c] = beta_[col];
    }
    #pragma unroll
    for (int j = 0; j < 4; ++j) {
        int r = m0 + quad * 4 + j;
        float y[8];
        float s1 = 0.f, s2 = 0.f;
        #pragma unroll
        for (int c = 0; c < 8; ++c) {
            float v = acc[c][j] + bb[c] + entity[r * 128 + c * 16 + lm];
            y[c] = v; s1 += v; s2 += v * v;
        }
        #pragma unroll
        for (int off = 8; off >= 1; off >>= 1) {
            s1 += __shfl_xor(s1, off, 16);
            s2 += __shfl_xor(s2, off, 16);
        }
        float mu  = s1 * (1.0f / 128.0f);
        float var = fmaxf(s2 * (1.0f / 128.0f) - mu * mu, 0.0f);
        float rs  = rsqrtf(var + LN_EPS);
        #pragma unroll
        for (int c = 0; c < 8; ++c)
            OUT[r * 128 + c * 16 + lm] = (y[c] - mu) * rs * gg[c] + be[c];
    }
}

// ===========================================================================
// FALLBACK (round-5 fused kernel, ~314 µs) — used if ws too small
// ===========================================================================
__global__ __launch_bounds__(256, 6) void rga_fused(
    const float* __restrict__ entity,
    const int* __restrict__ nidx,
    const int* __restrict__ nrel,
    const int* __restrict__ nmask,
    const float* __restrict__ Wq, const float* __restrict__ bq,
    const float* __restrict__ Wk, const float* __restrict__ bk,
    const float* __restrict__ Wv, const float* __restrict__ bv,
    const float* __restrict__ Wo, const float* __restrict__ bo,
    const float* __restrict__ rel_table,
    const float* __restrict__ gamma_, const float* __restrict__ beta_,
    float* __restrict__ outp) {
    __shared__ __align__(16) float er[128];
    __shared__ __align__(16) float qv[128];
    __shared__ float qb[8];
    __shared__ __align__(16) float qk[8 * 132];
    __shared__ __align__(16) unsigned int nbvp[32 * 68];
    __shared__ float Lg[8][33];
    __shared__ __align__(16) float pv[8 * 132];
    __shared__ __align__(16) float oat[128];
    __shared__ float ypart[2][128];
    __shared__ float red[4];
    __shared__ int midx[32], mrel[32], mmask[32];

    int m = blockIdx.x;
    int t = threadIdx.x;

    if (t < 32) {
        int mk = nmask[m * NNBR + t];
        int ix = nidx[m * NNBR + t];
        int ir = nrel[m * NNBR + t];
        if (!mk) { ix = 0; ir = 0; }
        ix = ix < 0 ? 0 : (ix > M_NODES - 1 ? M_NODES - 1 : ix);
        ir = ir < 0 ? 0 : (ir > RREL - 1 ? RREL - 1 : ir);
        mmask[t] = mk; midx[t] = ix; mrel[t] = ir;
    }
    if (t >= 128) er[t - 128] = entity[m * 128 + (t - 128)];
    __syncthreads();

    {
        int half = t >> 7, d = t & 127, j0 = half * 64;
        const float4v* e4 = (const float4v*)&er[j0];
        float acc = 0.f;
        #pragma unroll 4
        for (int c = 0; c < 16; ++c) {
            float4v ev = e4[c];
            #pragma unroll
            for (int k = 0; k < 4; ++k)
                acc += ev[k] * Wq[(j0 + c * 4 + k) * 128 + d];
        }
        ypart[half][d] = acc;
    }
    __syncthreads();
    if (t < 128) qv[t] = ypart[0][t] + ypart[1][t] + bq[t];
    __syncthreads();

    #pragma unroll
    for (int rep = 0; rep < 4; ++rep) {
        int o = rep * 256 + t;
        int h = o >> 7, j = o & 127;
        const float4v* wr = (const float4v*)&Wk[j * 128 + h * 16];
        const float4v* q4 = (const float4v*)&qv[h * 16];
        float s = 0.f;
        #pragma unroll
        for (int c = 0; c < 4; ++c) {
            float4v ww = wr[c], q = q4[c];
            #pragma unroll
            for (int k = 0; k < 4; ++k) s += ww[k] * q[k];
        }
        qk[h * 132 + j] = s;
    }
    if (t < 8) {
        float s = 0.f;
        #pragma unroll
        for (int dh = 0; dh < 16; ++dh) s += qv[t * 16 + dh] * bk[t * 16 + dh];
        qb[t] = s;
    }
    __syncthreads();

    {
        int n = t >> 3, c16 = t & 7, j0 = c16 * 16;
        int ix = midx[n], ir = mrel[n];
        const float4v* ep = (const float4v*)&entity[ix * 128 + j0];
        const float4v* rp = (const float4v*)&rel_table[ir * 128 + j0];
        float ev[16], kv[16];
        #pragma unroll
        for (int c = 0; c < 4; ++c) {
            float4v e4 = ep[c], r4 = rp[c];
            #pragma unroll
            for (int k = 0; k < 4; ++k) {
                ev[c * 4 + k] = e4[k];
                kv[c * 4 + k] = e4[k] + r4[k];
            }
        }
        uint4v u0, u1;
        #pragma unroll
        for (int k = 0; k < 4; ++k) u0[k] = pack2(ev[2 * k], ev[2 * k + 1]);
        #pragma unroll
        for (int k = 0; k < 4; ++k) u1[k] = pack2(ev[8 + 2 * k], ev[9 + 2 * k]);
        *(uint4v*)&nbvp[n * 68 + c16 * 8]     = u0;
        *(uint4v*)&nbvp[n * 68 + c16 * 8 + 4] = u1;
        float acc[8];
        #pragma unroll
        for (int h = 0; h < 8; ++h) {
            const float4v* qrow = (const float4v*)&qk[h * 132 + j0];
            float s = 0.f;
            #pragma unroll
            for (int c = 0; c < 4; ++c) {
                float4v q = qrow[c];
                #pragma unroll
                for (int k = 0; k < 4; ++k) s += q[k] * kv[c * 4 + k];
            }
            acc[h] = s;
        }
        #pragma unroll
        for (int off = 1; off < 8; off <<= 1) {
            #pragma unroll
            for (int h = 0; h < 8; ++h) acc[h] += __shfl_xor(acc[h], off, 8);
        }
        if (c16 == 0) {
            #pragma unroll
            for (int h = 0; h < 8; ++h) {
                float lf = (acc[h] + qb[h]) * ATTN_SCALE;
                if (!mmask[n]) lf = -1e30f;
                Lg[h][n] = lf;
            }
        }
    }
    __syncthreads();

    {
        int h = t >> 5, n = t & 31;
        float lf = Lg[h][n];
        float mx = lf;
        #pragma unroll
        for (int off = 16; off >= 1; off >>= 1) mx = fmaxf(mx, __shfl_xor(mx, off, 32));
        float p = __expf(lf - mx);
        float s = p;
        #pragma unroll
        for (int off = 16; off >= 1; off >>= 1) s += __shfl_xor(s, off, 32);
        Lg[h][n] = p / s;
    }
    __syncthreads();

    {
        int h = t >> 5, c4 = t & 31;
        float4v a = (float4v){0.f, 0.f, 0.f, 0.f};
        #pragma unroll 8
        for (int n = 0; n < 32; ++n) {
            float p = Lg[h][n];
            unsigned int w0 = nbvp[n * 68 + c4 * 2];
            unsigned int w1 = nbvp[n * 68 + c4 * 2 + 1];
            a[0] += p * unpk_lo(w0);
            a[1] += p * unpk_hi(w0);
            a[2] += p * unpk_lo(w1);
            a[3] += p * unpk_hi(w1);
        }
        *(float4v*)&pv[h * 132 + c4 * 4] = a;
    }
    __syncthreads();

    {
        int half = t >> 7, d = t & 127, j0 = half * 64;
        int h = d >> 4;
        const float4v* p4 = (const float4v*)&pv[h * 132 + j0];
        float acc = 0.f;
        #pragma unroll 4
        for (int c = 0; c < 16; ++c) {
            float4v p = p4[c];
            #pragma unroll
            for (int k = 0; k < 4; ++k)
                acc += p[k] * Wv[(j0 + c * 4 + k) * 128 + d];
        }
        ypart[half][d] = acc;
    }
    __syncthreads();
    if (t < 128) oat[t] = ypart[0][t] + ypart[1][t] + bv[t];
    __syncthreads();

    {
        int half = t >> 7, d = t & 127, j0 = half * 64;
        const float4v* o4 = (const float4v*)&oat[j0];
        float acc = 0.f;
        #pragma unroll 4
        for (int c = 0; c < 16; ++c) {
            float4v o = o4[c];
            #pragma unroll
            for (int k = 0; k < 4; ++k)
                acc += o[k] * Wo[(j0 + c * 4 + k) * 128 + d];
        }
        ypart[half][d] = acc;
    }
    __syncthreads();

    float x = 0.f;
    if (t < 128) {
        x = er[t] + ypart[0][t] + ypart[1][t] + bo[t];
        float s1 = x, s2 = x * x;
        #pragma unroll
        for (int off = 32; off >= 1; off >>= 1) {
            s1 += __shfl_xor(s1, off, 64);
            s2 += __shfl_xor(s2, off, 64);
        }
        if ((t & 63) == 0) { red[(t >> 6) * 2] = s1; red[(t >> 6) * 2 + 1] = s2; }
    }
    __syncthreads();
    if (t < 128) {
        float mu  = (red[0] + red[2]) * (1.0f / 128.0f);
        float ms  = (red[1] + red[3]) * (1.0f / 128.0f);
        float var = fmaxf(ms - mu * mu, 0.0f);
        float rs  = rsqrtf(var + LN_EPS);
        outp[m * 128 + t] = (x - mu) * rs * gamma_[t] + beta_[t];
    }
}

// ---------------------------------------------------------------------------
extern "C" void kernel_launch(void* const* d_in, const int* in_sizes, int n_in,
                              void* d_out, int out_size, void* d_ws, size_t ws_size,
                              hipStream_t stream) {
    const float* entity    = (const float*)d_in[0];
    const int*   nidx      = (const int*)d_in[1];
    const int*   nrel      = (const int*)d_in[2];
    const int*   nmask     = (const int*)d_in[3];
    const float* Wq        = (const float*)d_in[4];
    const float* bq        = (const float*)d_in[5];
    const float* Wk        = (const float*)d_in[6];
    const float* bk        = (const float*)d_in[7];
    const float* Wv        = (const float*)d_in[8];
    const float* bv        = (const float*)d_in[9];
    const float* Wo        = (const float*)d_in[10];
    const float* bo        = (const float*)d_in[11];
    const float* rel_table = (const float*)d_in[12];
    const float* gamma_    = (const float*)d_in[13];
    const float* beta_     = (const float*)d_in[14];

    // ws layout:
    //   Kb  (bf16) 4M     @ 0
    //   Vb  (bf16) 4M     @ 4194304
    //   EQb (bf16) 4M     @ 8388608
    //   OATb(bf16) 4M     @ 12582912
    //   RKb (bf16) 60672  @ 16777216
    //   WqT/WkT/WvT/WoT 32K each @ 16837888
    //   Eb  (bf16) 4M     @ 16968960
    //   PIX (u32)  2M     @ 21163264
    char* ws = (char*)d_ws;
    unsigned short* Kb   = (unsigned short*)(ws + 0);
    unsigned short* Vb   = (unsigned short*)(ws + 4194304);
    unsigned short* EQb  = (unsigned short*)(ws + 8388608);
    unsigned short* OATb = (unsigned short*)(ws + 12582912);
    unsigned short* RKb  = (unsigned short*)(ws + 16777216);
    unsigned short* WqT  = (unsigned short*)(ws + 16837888);
    unsigned short* WkT  = (unsigned short*)(ws + 16870656);
    unsigned short* WvT  = (unsigned short*)(ws + 16903424);
    unsigned short* WoT  = (unsigned short*)(ws + 16936192);
    unsigned short* Eb   = (unsigned short*)(ws + 16968960);
    unsigned int*   PIX  = (unsigned int*)(ws + 21163264);
    const size_t NEED = 21163264 + 2097152;

    if (ws_size >= NEED) {
        prep_w<<<dim3(224), 256, 0, stream>>>(Wq, Wk, Wv, Wo, entity,
                                              nidx, nrel, nmask,
                                              WqT, WkT, WvT, WoT, Eb, PIX);
        gemm4_mfma<<<dim3(256, 4), 256, 0, stream>>>(
            rel_table, Eb, WqT, WkT, WvT, bq, bk, bv, EQb, Kb, Vb, RKb);
        attn_gather<<<dim3(M_NODES / 4), 256, 0, stream>>>(
            PIX, EQb, Kb, Vb, RKb, OATb);
        gemm_wo_ln<<<dim3(256), 256, 0, stream>>>(
            OATb, WoT, bo, entity, gamma_, beta_, (float*)d_out);
    } else {
        rga_fused<<<dim3(M_NODES), 256, 0, stream>>>(
            entity, nidx, nrel, nmask, Wq, bq, Wk, bk, Wv, bv, Wo, bo,
            rel_table, gamma_, beta_, (float*)d_out);
    }
}

// Round 11
// 129.765 us; speedup vs baseline: 1.0664x; 1.0664x over previous
//
#include <hip/hip_runtime.h>

#define M_NODES 16384
#define NNBR 32
#define RREL 237
#define ATTN_SCALE 0.25f   // (128/8)^-0.5
#define LN_EPS 1e-5f

typedef float float4v __attribute__((ext_vector_type(4)));
typedef unsigned int uint4v __attribute__((ext_vector_type(4)));
typedef short short8 __attribute__((ext_vector_type(8)));
typedef float floatx4 __attribute__((ext_vector_type(4)));

__device__ __forceinline__ float bfu2f(unsigned short u) {
    return __builtin_bit_cast(float, ((unsigned int)u) << 16);
}
__device__ __forceinline__ unsigned short f2bfu(float f) {
    unsigned int x = __builtin_bit_cast(unsigned int, f);
    unsigned int lsb = (x >> 16) & 1u;
    x += 0x7fffu + lsb;                 // round-to-nearest-even
    return (unsigned short)(x >> 16);
}
__device__ __forceinline__ unsigned int pack2(float a, float b) {
    return (unsigned int)f2bfu(a) | ((unsigned int)f2bfu(b) << 16);
}
__device__ __forceinline__ float unpk_lo(unsigned int u) {
    return __builtin_bit_cast(float, u << 16);
}
__device__ __forceinline__ float unpk_hi(unsigned int u) {
    return __builtin_bit_cast(float, u & 0xffff0000u);
}

// ===========================================================================
// FAST PATH — 4 dispatches. Cost model: wall = ~40 fixed + ~45 ws-fill
// + sum(kernels). Never use device barriers (r11).
// r21 (confirmed, 136.8->130.9): K2 was TCP address-divergence-bound; K/R
// rows loaded row-contiguously (8 seg/instr vs 16) + LDS half-buffer
// transpose to MFMA fragment layout. r22 (REVERTED, 138.4): delaying R
// loads after K-h1 staging killed memory-level parallelism — keep K+R
// issued together up-front. MLP > occupancy in this kernel (r16/r19/r22).
// ===========================================================================

// K0: weight transpose+convert (blocks 0..31) + entity fp32->bf16 (32..159)
//     + neighbor (mask,idx,rel) -> packed PIX (160..223).
__global__ __launch_bounds__(256) void prep_w(
    const float* __restrict__ Wq, const float* __restrict__ Wk,
    const float* __restrict__ Wv, const float* __restrict__ Wo,
    const float* __restrict__ entity,
    const int* __restrict__ nidx, const int* __restrict__ nrel,
    const int* __restrict__ nmask,
    unsigned short* __restrict__ WqT, unsigned short* __restrict__ WkT,
    unsigned short* __restrict__ WvT, unsigned short* __restrict__ WoT,
    unsigned short* __restrict__ Eb, unsigned int* __restrict__ PIX) {
    int t = threadIdx.x;
    if (blockIdx.x < 32) {
        int mat  = blockIdx.x >> 3;
        int slab = blockIdx.x & 7;
        const float* W = (mat == 0) ? Wq : (mat == 1) ? Wk : (mat == 2) ? Wv : Wo;
        unsigned short* WT = (mat == 0) ? WqT : (mat == 1) ? WkT : (mat == 2) ? WvT : WoT;
        #pragma unroll
        for (int i = 0; i < 8; ++i) {
            int idx = t + 256 * i;
            int r = slab * 16 + (idx >> 7);
            int c = idx & 127;
            WT[c * 128 + r] = f2bfu(W[r * 128 + c]);
        }
    } else if (blockIdx.x < 160) {
        // 128 blocks x 256 thr x 8 iters x 8 elems = 16384*128 elements
        int b = blockIdx.x - 32;
        const float* src = entity + (size_t)b * 16384;
        unsigned short* dst = Eb + (size_t)b * 16384;
        #pragma unroll
        for (int i = 0; i < 8; ++i) {
            int o = (i * 256 + t) * 8;
            float4v f0 = *(const float4v*)&src[o];
            float4v f1 = *(const float4v*)&src[o + 4];
            short8 s;
            #pragma unroll
            for (int j = 0; j < 4; ++j) {
                s[j]     = (short)f2bfu(f0[j]);
                s[4 + j] = (short)f2bfu(f1[j]);
            }
            *(short8*)&dst[o] = s;
        }
    } else {
        // 64 blocks x 256 thr x 32 entries = 524288 packed neighbor records
        int base = (blockIdx.x - 160) * 8192;
        #pragma unroll 8
        for (int i = 0; i < 32; ++i) {
            int e = base + i * 256 + t;
            int mk = nmask[e];
            int ix = nidx[e];
            int ir = nrel[e];
            if (!mk) { ix = 0; ir = 0; }
            ix = ix < 0 ? 0 : (ix > M_NODES - 1 ? M_NODES - 1 : ix);
            ir = ir < 0 ? 0 : (ir > RREL - 1 ? RREL - 1 : ir);
            PIX[e] = (unsigned)ix | ((unsigned)ir << 14) | (mk ? 0x80000000u : 0u);
        }
    }
}

// K1: four projections. grid (256, 4), 64 rows/block (proven r1 form):
//   y=0: EQb; y=1: Kb; y=2: Vb; y=3: RKb (237 rows).
__global__ __launch_bounds__(256) void gemm4_mfma(
    const float* __restrict__ rel_table, const unsigned short* __restrict__ Eb,
    const unsigned short* __restrict__ WqT, const unsigned short* __restrict__ WkT,
    const unsigned short* __restrict__ WvT,
    const float* __restrict__ bq, const float* __restrict__ bk,
    const float* __restrict__ bv,
    unsigned short* __restrict__ EQb, unsigned short* __restrict__ Kb,
    unsigned short* __restrict__ Vb, unsigned short* __restrict__ RKb) {
    __shared__ __align__(16) unsigned short lw[128 * 136];

    int y = blockIdx.y;
    const unsigned short* WT; const float* bias; int arows;
    unsigned short* outb;
    if (y == 0)      { WT = WqT; bias = bq;      arows = M_NODES; outb = EQb; }
    else if (y == 1) { WT = WkT; bias = nullptr; arows = M_NODES; outb = Kb;  }
    else if (y == 2) { WT = WvT; bias = bv;      arows = M_NODES; outb = Vb;  }
    else             { WT = WkT; bias = bk;      arows = RREL;    outb = RKb; }

    int rbase = blockIdx.x * 64;
    if (rbase >= arows) return;
    int t = threadIdx.x;
    int wave = t >> 6, lane = t & 63;
    int lm = lane & 15, quad = lane >> 4;
    int m0 = rbase + wave * 16;
    int r0 = m0 + lm; if (r0 >= arows) r0 = arows - 1;

    // A-fragments hoisted before staging: loads fly under the LDS fill.
    short8 af[4];
    if (y == 3) {
        #pragma unroll
        for (int ks = 0; ks < 4; ++ks) {
            int koff = ks * 32 + quad * 8;
            float4v f0 = *(const float4v*)&rel_table[r0 * 128 + koff];
            float4v f1 = *(const float4v*)&rel_table[r0 * 128 + koff + 4];
            #pragma unroll
            for (int j = 0; j < 4; ++j) {
                af[ks][j]     = (short)f2bfu(f0[j]);
                af[ks][4 + j] = (short)f2bfu(f1[j]);
            }
        }
    } else {
        #pragma unroll
        for (int ks = 0; ks < 4; ++ks)
            af[ks] = *(const short8*)&Eb[r0 * 128 + ks * 32 + quad * 8];
    }

    #pragma unroll
    for (int i = 0; i < 8; ++i) {
        int ci = t + 256 * i;
        int r  = ci >> 4;
        int c8 = ci & 15;
        *(short8*)&lw[r * 136 + c8 * 8] = *(const short8*)&WT[r * 128 + c8 * 8];
    }
    __syncthreads();

    floatx4 acc[8];
    #pragma unroll
    for (int c = 0; c < 8; ++c) acc[c] = (floatx4){0.f, 0.f, 0.f, 0.f};

    #pragma unroll
    for (int ks = 0; ks < 4; ++ks) {
        int koff = ks * 32 + quad * 8;
        #pragma unroll
        for (int c = 0; c < 8; ++c) {
            short8 b = *(const short8*)&lw[(c * 16 + lm) * 136 + koff];
            acc[c] = __builtin_amdgcn_mfma_f32_16x16x32_bf16(af[ks], b, acc[c], 0, 0, 0);
        }
    }

    #pragma unroll
    for (int c = 0; c < 8; ++c) {
        int col = c * 16 + lm;
        float bb = bias ? bias[col] : 0.0f;
        int rb = m0 + quad * 4;
        #pragma unroll
        for (int j = 0; j < 4; ++j) {
            int r = rb + j;
            if (r < arows) outb[r * 128 + col] = f2bfu(acc[c][j] + bb);
        }
    }
}

// K2: wave-per-node attention. grid 4096 x 256 (4 nodes/block).
// r21: K and R rows loaded ROW-CONTIGUOUSLY (lane l&15 covers 16B chunk of
// row i*4+(l>>4): 8 segments/instr, 8 instrs each) then transposed to MFMA
// fragment layout via a 16-row wave-private LDS half-buffer (272B stride:
// 2-way read conflicts only), reused for K-h0/K-h1/R-h0/R-h1.
// fp32 accum reassociated (all-K then all-R) — same values mod fp32 order.
// V already row-contiguous (8 seg/instr). Softmax/PV unchanged from r17/18.
__global__ __launch_bounds__(256, 6) void attn_gather(
    const unsigned int* __restrict__ PIX,
    const unsigned short* __restrict__ EQb, const unsigned short* __restrict__ Kb,
    const unsigned short* __restrict__ Vb, const unsigned short* __restrict__ RKb,
    unsigned short* __restrict__ OATb) {
    __shared__ float Pl[4][8][33];
    __shared__ __align__(16) unsigned short Kst[4][16 * 136];   // 4.25KB/wave

    int w = threadIdx.x >> 6, l = threadIdx.x & 63;
    int m = blockIdx.x * 4 + w;
    int lm = l & 15, quad = l >> 4;
    int n0 = l & 31;
    int cs = l & 15;     // chunk slot (16B units within a 256B row)
    int rs = l >> 4;     // row slot (4 rows per load instruction)

    // ---- single packed neighbor record: ix(14) | ir(8)<<14 | mk<<31 ----
    unsigned pix = PIX[m * NNBR + n0];

    // q depends only on m — wave-uniform row, 1 segment per load.
    short8 q8v[4];
    #pragma unroll
    for (int ks = 0; ks < 4; ++ks)
        q8v[ks] = *(const short8*)&EQb[m * 128 + ks * 32 + quad * 8];

    int ix = (int)(pix & 0x3FFFu);
    int ir = (int)((pix >> 14) & 0xFFu);
    unsigned long long bal = __ballot((pix >> 31) != 0);
    unsigned maskbits = (unsigned)(bal & 0xffffffffu);   // bit n = mask of nbr n

    // ---- row-contiguous K loads: instr i covers rows i*4..i*4+3 fully ----
    short8 kreg[8];
    #pragma unroll
    for (int i = 0; i < 8; ++i) {
        int rK = __shfl(ix, i * 4 + rs, 64);
        kreg[i] = *(const short8*)&Kb[rK * 128 + cs * 8];
    }
    // ---- row-contiguous R loads (L2-hot table, same shape) ----
    short8 rreg[8];
    #pragma unroll
    for (int i = 0; i < 8; ++i) {
        int rR = __shfl(ir, i * 4 + rs, 64);
        rreg[i] = *(const short8*)&RKb[rR * 128 + cs * 8];
    }

    floatx4 acc0 = (floatx4){0.f, 0.f, 0.f, 0.f};
    floatx4 acc1 = (floatx4){0.f, 0.f, 0.f, 0.f};
    const short8 zero8 = (short8){0, 0, 0, 0, 0, 0, 0, 0};
    unsigned short* kw = &Kst[w][0];

    // ---- K half 0 (rows 0..15) : stage -> consume ----
    #pragma unroll
    for (int i = 0; i < 4; ++i)
        *(short8*)&kw[(i * 4 + rs) * 136 + cs * 8] = kreg[i];
    #pragma unroll
    for (int ks = 0; ks < 4; ++ks) {
        int h = ks * 2 + (quad >> 1);
        short8 bq = (lm == h) ? q8v[ks] : zero8;
        short8 kf = *(const short8*)&kw[lm * 136 + (ks * 4 + quad) * 8];
        acc0 = __builtin_amdgcn_mfma_f32_16x16x32_bf16(kf, bq, acc0, 0, 0, 0);
    }
    // ---- K half 1 (rows 16..31) ----
    #pragma unroll
    for (int i = 0; i < 4; ++i)
        *(short8*)&kw[(i * 4 + rs) * 136 + cs * 8] = kreg[4 + i];
    #pragma unroll
    for (int ks = 0; ks < 4; ++ks) {
        int h = ks * 2 + (quad >> 1);
        short8 bq = (lm == h) ? q8v[ks] : zero8;
        short8 kf = *(const short8*)&kw[lm * 136 + (ks * 4 + quad) * 8];
        acc1 = __builtin_amdgcn_mfma_f32_16x16x32_bf16(kf, bq, acc1, 0, 0, 0);
    }
    // ---- R half 0 ----
    #pragma unroll
    for (int i = 0; i < 4; ++i)
        *(short8*)&kw[(i * 4 + rs) * 136 + cs * 8] = rreg[i];
    #pragma unroll
    for (int ks = 0; ks < 4; ++ks) {
        int h = ks * 2 + (quad >> 1);
        short8 bq = (lm == h) ? q8v[ks] : zero8;
        short8 rf = *(const short8*)&kw[lm * 136 + (ks * 4 + quad) * 8];
        acc0 = __builtin_amdgcn_mfma_f32_16x16x32_bf16(rf, bq, acc0, 0, 0, 0);
    }
    // ---- R half 1 ----
    #pragma unroll
    for (int i = 0; i < 4; ++i)
        *(short8*)&kw[(i * 4 + rs) * 136 + cs * 8] = rreg[4 + i];
    #pragma unroll
    for (int ks = 0; ks < 4; ++ks) {
        int h = ks * 2 + (quad >> 1);
        short8 bq = (lm == h) ? q8v[ks] : zero8;
        short8 rf = *(const short8*)&kw[lm * 136 + (ks * 4 + quad) * 8];
        acc1 = __builtin_amdgcn_mfma_f32_16x16x32_bf16(rf, bq, acc1, 0, 0, 0);
    }

    // ---- V gather (already row-contiguous: 4 rows x full 256B per instr) --
    uint4v vreg[8];
    #pragma unroll
    for (int i = 0; i < 8; ++i) {
        int ixx = __shfl(ix, quad + i * 4, 64);
        vreg[i] = *(const uint4v*)&Vb[ixx * 128 + lm * 8];
    }

    // ---- masked softmax in C-layout (head = lm, n = g*16 + quad*4 + j) ----
    float lf[2][4];
    #pragma unroll
    for (int j = 0; j < 4; ++j) {
        int na = quad * 4 + j, nb = 16 + quad * 4 + j;
        float va = acc0[j] * ATTN_SCALE;
        float vb = acc1[j] * ATTN_SCALE;
        lf[0][j] = ((maskbits >> na) & 1) ? va : -1e30f;
        lf[1][j] = ((maskbits >> nb) & 1) ? vb : -1e30f;
    }
    float mx = -1e30f;
    #pragma unroll
    for (int g = 0; g < 2; ++g)
        #pragma unroll
        for (int j = 0; j < 4; ++j) mx = fmaxf(mx, lf[g][j]);
    mx = fmaxf(mx, __shfl_xor(mx, 16, 64));
    mx = fmaxf(mx, __shfl_xor(mx, 32, 64));
    float p[2][4];
    float s = 0.f;
    #pragma unroll
    for (int g = 0; g < 2; ++g)
        #pragma unroll
        for (int j = 0; j < 4; ++j) { p[g][j] = __expf(lf[g][j] - mx); s += p[g][j]; }
    s += __shfl_xor(s, 16, 64);
    s += __shfl_xor(s, 32, 64);
    float inv = 1.0f / s;
    if (lm < 8) {
        #pragma unroll
        for (int g = 0; g < 2; ++g)
            #pragma unroll
            for (int j = 0; j < 4; ++j)
                Pl[w][lm][g * 16 + quad * 4 + j] = p[g][j] * inv;
    }

    // ---- PV from vreg (same-wave LDS, no barrier); hi/lo unpack ----
    float o[8] = {0.f, 0.f, 0.f, 0.f, 0.f, 0.f, 0.f, 0.f};
    #pragma unroll
    for (int i = 0; i < 8; ++i) {
        float pp = Pl[w][lm >> 1][quad + i * 4];
        uint4v v = vreg[i];
        #pragma unroll
        for (int k = 0; k < 4; ++k) {
            o[2 * k]     += pp * unpk_lo(v[k]);
            o[2 * k + 1] += pp * unpk_hi(v[k]);
        }
    }
    #pragma unroll
    for (int j = 0; j < 8; ++j) {
        o[j] += __shfl_xor(o[j], 16, 64);
        o[j] += __shfl_xor(o[j], 32, 64);
    }
    if (quad == 0) {
        uint4v u;
        u[0] = pack2(o[0], o[1]); u[1] = pack2(o[2], o[3]);
        u[2] = pack2(o[4], o[5]); u[3] = pack2(o[6], o[7]);
        *(uint4v*)&OATb[m * 128 + lm * 8] = u;
    }
}

// K3: Y = OATb@Wo + bo + entity -> LayerNorm. grid 256, 256 thr
// (4 waves x 16 rows; B staged in LDS — proven r1 form).
__global__ __launch_bounds__(256) void gemm_wo_ln(
    const unsigned short* __restrict__ OATb, const unsigned short* __restrict__ WoT,
    const float* __restrict__ bo, const float* __restrict__ entity,
    const float* __restrict__ gamma_, const float* __restrict__ beta_,
    float* __restrict__ OUT) {
    __shared__ __align__(16) unsigned short lw[128 * 136];

    int t = threadIdx.x;
    int wave = t >> 6, lane = t & 63;
    int lm = lane & 15, quad = lane >> 4;
    int m0 = blockIdx.x * 64 + wave * 16;
    int r0 = m0 + lm;

    // A-fragments hoisted before staging.
    short8 af[4];
    #pragma unroll
    for (int ks = 0; ks < 4; ++ks)
        af[ks] = *(const short8*)&OATb[r0 * 128 + ks * 32 + quad * 8];

    #pragma unroll
    for (int i = 0; i < 8; ++i) {
        int ci = t + 256 * i;
        int r  = ci >> 4;
        int c8 = ci & 15;
        *(short8*)&lw[r * 136 + c8 * 8] = *(const short8*)&WoT[r * 128 + c8 * 8];
    }
    __syncthreads();

    floatx4 acc[8];
    #pragma unroll
    for (int c = 0; c < 8; ++c) acc[c] = (floatx4){0.f, 0.f, 0.f, 0.f};

    #pragma unroll
    for (int ks = 0; ks < 4; ++ks) {
        int koff = ks * 32 + quad * 8;
        #pragma unroll
        for (int c = 0; c < 8; ++c) {
            short8 b = *(const short8*)&lw[(c * 16 + lm) * 136 + koff];
            acc[c] = __builtin_amdgcn_mfma_f32_16x16x32_bf16(af[ks], b, acc[c], 0, 0, 0);
        }
    }

    float bb[8], gg[8], be[8];
    #pragma unroll
    for (int c = 0; c < 8; ++c) {
        int col = c * 16 + lm;
        bb[c] = bo[col]; gg[c] = gamma_[col]; be[c] = beta_[col];
    }
    #pragma unroll
    for (int j = 0; j < 4; ++j) {
        int r = m0 + quad * 4 + j;
        float y[8];
        float s1 = 0.f, s2 = 0.f;
        #pragma unroll
        for (int c = 0; c < 8; ++c) {
            float v = acc[c][j] + bb[c] + entity[r * 128 + c * 16 + lm];
            y[c] = v; s1 += v; s2 += v * v;
        }
        #pragma unroll
        for (int off = 8; off >= 1; off >>= 1) {
            s1 += __shfl_xor(s1, off, 16);
            s2 += __shfl_xor(s2, off, 16);
        }
        float mu  = s1 * (1.0f / 128.0f);
        float var = fmaxf(s2 * (1.0f / 128.0f) - mu * mu, 0.0f);
        float rs  = rsqrtf(var + LN_EPS);
        #pragma unroll
        for (int c = 0; c < 8; ++c)
            OUT[r * 128 + c * 16 + lm] = (y[c] - mu) * rs * gg[c] + be[c];
    }
}

// ===========================================================================
// FALLBACK (round-5 fused kernel, ~314 µs) — used if ws too small
// ===========================================================================
__global__ __launch_bounds__(256, 6) void rga_fused(
    const float* __restrict__ entity,
    const int* __restrict__ nidx,
    const int* __restrict__ nrel,
    const int* __restrict__ nmask,
    const float* __restrict__ Wq, const float* __restrict__ bq,
    const float* __restrict__ Wk, const float* __restrict__ bk,
    const float* __restrict__ Wv, const float* __restrict__ bv,
    const float* __restrict__ Wo, const float* __restrict__ bo,
    const float* __restrict__ rel_table,
    const float* __restrict__ gamma_, const float* __restrict__ beta_,
    float* __restrict__ outp) {
    __shared__ __align__(16) float er[128];
    __shared__ __align__(16) float qv[128];
    __shared__ float qb[8];
    __shared__ __align__(16) float qk[8 * 132];
    __shared__ __align__(16) unsigned int nbvp[32 * 68];
    __shared__ float Lg[8][33];
    __shared__ __align__(16) float pv[8 * 132];
    __shared__ __align__(16) float oat[128];
    __shared__ float ypart[2][128];
    __shared__ float red[4];
    __shared__ int midx[32], mrel[32], mmask[32];

    int m = blockIdx.x;
    int t = threadIdx.x;

    if (t < 32) {
        int mk = nmask[m * NNBR + t];
        int ix = nidx[m * NNBR + t];
        int ir = nrel[m * NNBR + t];
        if (!mk) { ix = 0; ir = 0; }
        ix = ix < 0 ? 0 : (ix > M_NODES - 1 ? M_NODES - 1 : ix);
        ir = ir < 0 ? 0 : (ir > RREL - 1 ? RREL - 1 : ir);
        mmask[t] = mk; midx[t] = ix; mrel[t] = ir;
    }
    if (t >= 128) er[t - 128] = entity[m * 128 + (t - 128)];
    __syncthreads();

    {
        int half = t >> 7, d = t & 127, j0 = half * 64;
        const float4v* e4 = (const float4v*)&er[j0];
        float acc = 0.f;
        #pragma unroll 4
        for (int c = 0; c < 16; ++c) {
            float4v ev = e4[c];
            #pragma unroll
            for (int k = 0; k < 4; ++k)
                acc += ev[k] * Wq[(j0 + c * 4 + k) * 128 + d];
        }
        ypart[half][d] = acc;
    }
    __syncthreads();
    if (t < 128) qv[t] = ypart[0][t] + ypart[1][t] + bq[t];
    __syncthreads();

    #pragma unroll
    for (int rep = 0; rep < 4; ++rep) {
        int o = rep * 256 + t;
        int h = o >> 7, j = o & 127;
        const float4v* wr = (const float4v*)&Wk[j * 128 + h * 16];
        const float4v* q4 = (const float4v*)&qv[h * 16];
        float s = 0.f;
        #pragma unroll
        for (int c = 0; c < 4; ++c) {
            float4v ww = wr[c], q = q4[c];
            #pragma unroll
            for (int k = 0; k < 4; ++k) s += ww[k] * q[k];
        }
        qk[h * 132 + j] = s;
    }
    if (t < 8) {
        float s = 0.f;
        #pragma unroll
        for (int dh = 0; dh < 16; ++dh) s += qv[t * 16 + dh] * bk[t * 16 + dh];
        qb[t] = s;
    }
    __syncthreads();

    {
        int n = t >> 3, c16 = t & 7, j0 = c16 * 16;
        int ix = midx[n], ir = mrel[n];
        const float4v* ep = (const float4v*)&entity[ix * 128 + j0];
        const float4v* rp = (const float4v*)&rel_table[ir * 128 + j0];
        float ev[16], kv[16];
        #pragma unroll
        for (int c = 0; c < 4; ++c) {
            float4v e4 = ep[c], r4 = rp[c];
            #pragma unroll
            for (int k = 0; k < 4; ++k) {
                ev[c * 4 + k] = e4[k];
                kv[c * 4 + k] = e4[k] + r4[k];
            }
        }
        uint4v u0, u1;
        #pragma unroll
        for (int k = 0; k < 4; ++k) u0[k] = pack2(ev[2 * k], ev[2 * k + 1]);
        #pragma unroll
        for (int k = 0; k < 4; ++k) u1[k] = pack2(ev[8 + 2 * k], ev[9 + 2 * k]);
        *(uint4v*)&nbvp[n * 68 + c16 * 8]     = u0;
        *(uint4v*)&nbvp[n * 68 + c16 * 8 + 4] = u1;
        float acc[8];
        #pragma unroll
        for (int h = 0; h < 8; ++h) {
            const float4v* qrow = (const float4v*)&qk[h * 132 + j0];
            float s = 0.f;
            #pragma unroll
            for (int c = 0; c < 4; ++c) {
                float4v q = qrow[c];
                #pragma unroll
                for (int k = 0; k < 4; ++k) s += q[k] * kv[c * 4 + k];
            }
            acc[h] = s;
        }
        #pragma unroll
        for (int off = 1; off < 8; off <<= 1) {
            #pragma unroll
            for (int h = 0; h < 8; ++h) acc[h] += __shfl_xor(acc[h], off, 8);
        }
        if (c16 == 0) {
            #pragma unroll
            for (int h = 0; h < 8; ++h) {
                float lf = (acc[h] + qb[h]) * ATTN_SCALE;
                if (!mmask[n]) lf = -1e30f;
                Lg[h][n] = lf;
            }
        }
    }
    __syncthreads();

    {
        int h = t >> 5, n = t & 31;
        float lf = Lg[h][n];
        float mx = lf;
        #pragma unroll
        for (int off = 16; off >= 1; off >>= 1) mx = fmaxf(mx, __shfl_xor(mx, off, 32));
        float p = __expf(lf - mx);
        float s = p;
        #pragma unroll
        for (int off = 16; off >= 1; off >>= 1) s += __shfl_xor(s, off, 32);
        Lg[h][n] = p / s;
    }
    __syncthreads();

    {
        int h = t >> 5, c4 = t & 31;
        float4v a = (float4v){0.f, 0.f, 0.f, 0.f};
        #pragma unroll 8
        for (int n = 0; n < 32; ++n) {
            float p = Lg[h][n];
            unsigned int w0 = nbvp[n * 68 + c4 * 2];
            unsigned int w1 = nbvp[n * 68 + c4 * 2 + 1];
            a[0] += p * unpk_lo(w0);
            a[1] += p * unpk_hi(w0);
            a[2] += p * unpk_lo(w1);
            a[3] += p * unpk_hi(w1);
        }
        *(float4v*)&pv[h * 132 + c4 * 4] = a;
    }
    __syncthreads();

    {
        int half = t >> 7, d = t & 127, j0 = half * 64;
        int h = d >> 4;
        const float4v* p4 = (const float4v*)&pv[h * 132 + j0];
        float acc = 0.f;
        #pragma unroll 4
        for (int c = 0; c < 16; ++c) {
            float4v p = p4[c];
            #pragma unroll
            for (int k = 0; k < 4; ++k)
                acc += p[k] * Wv[(j0 + c * 4 + k) * 128 + d];
        }
        ypart[half][d] = acc;
    }
    __syncthreads();
    if (t < 128) oat[t] = ypart[0][t] + ypart[1][t] + bv[t];
    __syncthreads();

    {
        int half = t >> 7, d = t & 127, j0 = half * 64;
        const float4v* o4 = (const float4v*)&oat[j0];
        float acc = 0.f;
        #pragma unroll 4
        for (int c = 0; c < 16; ++c) {
            float4v o = o4[c];
            #pragma unroll
            for (int k = 0; k < 4; ++k)
                acc += o[k] * Wo[(j0 + c * 4 + k) * 128 + d];
        }
        ypart[half][d] = acc;
    }
    __syncthreads();

    float x = 0.f;
    if (t < 128) {
        x = er[t] + ypart[0][t] + ypart[1][t] + bo[t];
        float s1 = x, s2 = x * x;
        #pragma unroll
        for (int off = 32; off >= 1; off >>= 1) {
            s1 += __shfl_xor(s1, off, 64);
            s2 += __shfl_xor(s2, off, 64);
        }
        if ((t & 63) == 0) { red[(t >> 6) * 2] = s1; red[(t >> 6) * 2 + 1] = s2; }
    }
    __syncthreads();
    if (t < 128) {
        float mu  = (red[0] + red[2]) * (1.0f / 128.0f);
        float ms  = (red[1] + red[3]) * (1.0f / 128.0f);
        float var = fmaxf(ms - mu * mu, 0.0f);
        float rs  = rsqrtf(var + LN_EPS);
        outp[m * 128 + t] = (x - mu) * rs * gamma_[t] + beta_[t];
    }
}

// ---------------------------------------------------------------------------
extern "C" void kernel_launch(void* const* d_in, const int* in_sizes, int n_in,
                              void* d_out, int out_size, void* d_ws, size_t ws_size,
                              hipStream_t stream) {
    const float* entity    = (const float*)d_in[0];
    const int*   nidx      = (const int*)d_in[1];
    const int*   nrel      = (const int*)d_in[2];
    const int*   nmask     = (const int*)d_in[3];
    const float* Wq        = (const float*)d_in[4];
    const float* bq        = (const float*)d_in[5];
    const float* Wk        = (const float*)d_in[6];
    const float* bk        = (const float*)d_in[7];
    const float* Wv        = (const float*)d_in[8];
    const float* bv        = (const float*)d_in[9];
    const float* Wo        = (const float*)d_in[10];
    const float* bo        = (const float*)d_in[11];
    const float* rel_table = (const float*)d_in[12];
    const float* gamma_    = (const float*)d_in[13];
    const float* beta_     = (const float*)d_in[14];

    // ws layout:
    //   Kb  (bf16) 4M     @ 0
    //   Vb  (bf16) 4M     @ 4194304
    //   EQb (bf16) 4M     @ 8388608
    //   OATb(bf16) 4M     @ 12582912
    //   RKb (bf16) 60672  @ 16777216
    //   WqT/WkT/WvT/WoT 32K each @ 16837888
    //   Eb  (bf16) 4M     @ 16968960
    //   PIX (u32)  2M     @ 21163264
    char* ws = (char*)d_ws;
    unsigned short* Kb   = (unsigned short*)(ws + 0);
    unsigned short* Vb   = (unsigned short*)(ws + 4194304);
    unsigned short* EQb  = (unsigned short*)(ws + 8388608);
    unsigned short* OATb = (unsigned short*)(ws + 12582912);
    unsigned short* RKb  = (unsigned short*)(ws + 16777216);
    unsigned short* WqT  = (unsigned short*)(ws + 16837888);
    unsigned short* WkT  = (unsigned short*)(ws + 16870656);
    unsigned short* WvT  = (unsigned short*)(ws + 16903424);
    unsigned short* WoT  = (unsigned short*)(ws + 16936192);
    unsigned short* Eb   = (unsigned short*)(ws + 16968960);
    unsigned int*   PIX  = (unsigned int*)(ws + 21163264);
    const size_t NEED = 21163264 + 2097152;

    if (ws_size >= NEED) {
        prep_w<<<dim3(224), 256, 0, stream>>>(Wq, Wk, Wv, Wo, entity,
                                              nidx, nrel, nmask,
                                              WqT, WkT, WvT, WoT, Eb, PIX);
        gemm4_mfma<<<dim3(256, 4), 256, 0, stream>>>(
            rel_table, Eb, WqT, WkT, WvT, bq, bk, bv, EQb, Kb, Vb, RKb);
        attn_gather<<<dim3(M_NODES / 4), 256, 0, stream>>>(
            PIX, EQb, Kb, Vb, RKb, OATb);
        gemm_wo_ln<<<dim3(256), 256, 0, stream>>>(
            OATb, WoT, bo, entity, gamma_, beta_, (float*)d_out);
    } else {
        rga_fused<<<dim3(M_NODES), 256, 0, stream>>>(
            entity, nidx, nrel, nmask, Wq, bq, Wk, bk, Wv, bv, Wo, bo,
            rel_table, gamma_, beta_, (float*)d_out);
    }
}